// Round 3
// baseline (236.993 us; speedup 1.0000x reference)
//
#include <hip/hip_runtime.h>
#include <cstdint>
#include <cstddef>

// CNLinkPredictor on MI355X — round 2 resubmit (container died before bench).
//
// Pipeline (unchanged structure):
//   1. k_bitmask : adj (256 MB fp32 0/1) -> bit rows [N][128] u64  (HBM floor ~41 us)
//   2..3. gemm   : H = x + relu(relu(x@w1+b1)@w2+b2)
//   4. k_edges   : mask = bits[i]&bits[j]; xcn[e] = sum_k H[k]; xij_in = xi*xj
//   5..8. gemm   : xij MLP, xcn MLP(2), lin1 (z = xcn*beta + xij fused in A-stage)
//   9. k_gemv_out: out = L1 @ lin_w2 + b2
//
// GEMM: fp32 accuracy via split-bf16 (a = hi + lo, 3 MFMAs: HH + HL + LH).
// BM=128 BN=64 BK=64, 4 waves, wave tile 64x32, mfma_f32_16x16x32_bf16.
// LDS: A[128][64] + B^T[64][64], hi/lo planes, XOR chunk swizzle k^=(row&7)<<3
// -> frag ds_read_b128 uniform over 8 bank-groups (conflict-free), 16B aligned.

#define C_DIM   256
#define N_NODES 8192
#define E_EDGES 8192

typedef short bf16x8 __attribute__((ext_vector_type(8)));
typedef float f32x4  __attribute__((ext_vector_type(4)));

__device__ __forceinline__ unsigned short bf16_rne(float a) {
    unsigned u = __float_as_uint(a);
    u += 0x7FFFu + ((u >> 16) & 1u);
    return (unsigned short)(u >> 16);
}

// ---------------- kernel 1: adjacency -> bitmask ----------------
__global__ __launch_bounds__(256) void k_bitmask(const float* __restrict__ adj,
                                                 unsigned long long* __restrict__ bits) {
    const long long TOTAL = (long long)N_NODES * N_NODES / 64;  // 1M words
    const int  lane = threadIdx.x & 63;
    long long wid = (((long long)blockIdx.x * blockDim.x) + threadIdx.x) >> 6;
    long long nw  = ((long long)gridDim.x * blockDim.x) >> 6;
    for (long long w = wid; w < TOTAL; w += nw) {
        float v = adj[(w << 6) + lane];              // 64 lanes x 4B contiguous
        unsigned long long m = __ballot(v > 0.5f);
        if (lane == 0) bits[w] = m;
    }
}

// ---------------- split-bf16 MFMA GEMM ----------------
// C = act(A' @ B + bias) [+resid],  A' = A*beta + A2 when FUSE_Z.
// A:[M,256] rm fp32, B:[256,256] rm fp32 (K rows, N cols). M multiple of 128.
template<bool FUSE_Z, bool RESID, bool RELU>
__global__ __launch_bounds__(256, 1) void k_gemm_mfma(
    const float* __restrict__ A, const float* __restrict__ A2,
    const float* __restrict__ betap,
    const float* __restrict__ B, const float* __restrict__ bias,
    const float* __restrict__ resid, float* __restrict__ Cout)
{
    __shared__ short AsH[128][64];
    __shared__ short AsL[128][64];
    __shared__ short BsH[64][64];    // transposed: [n][k]
    __shared__ short BsL[64][64];

    const int t    = threadIdx.x;
    const int lane = t & 63;
    const int w    = t >> 6;                 // wave 0..3
    const int m0   = blockIdx.x * 128;
    const int n0   = blockIdx.y * 64;
    const int wm   = (w >> 1) * 64;          // wave m-offset in tile
    const int wn   = (w & 1) * 32;           // wave n-offset in tile
    const int fr   = lane & 15;              // frag row (A) / col (B)
    const int q    = lane >> 4;              // quarter -> k chunk / C row group

    const float beta = FUSE_Z ? betap[0] : 0.f;

    f32x4 acc[4][2];
    #pragma unroll
    for (int i = 0; i < 4; ++i)
        #pragma unroll
        for (int j = 0; j < 2; ++j)
            #pragma unroll
            for (int r = 0; r < 4; ++r) acc[i][j][r] = 0.f;

    // staging coords
    const int sa_r  = t >> 4;                // 0..15 row-within-pass
    const int sa_k  = (t & 15) << 2;         // 0..60 (float4)
    const int sb_n  = t & 63;                // B col (-> Bs row)
    const int sb_k0 = (t >> 6) << 4;         // wave handles 16 k-rows

    for (int k0 = 0; k0 < C_DIM; k0 += 64) {
        // ---- stage A tile 128x64, split hi/lo, swizzled ----
        #pragma unroll
        for (int p = 0; p < 8; ++p) {
            const int m = (p << 4) + sa_r;
            float4 a = *(const float4*)&A[(size_t)(m0 + m) * C_DIM + k0 + sa_k];
            if (FUSE_Z) {
                float4 a2 = *(const float4*)&A2[(size_t)(m0 + m) * C_DIM + k0 + sa_k];
                a.x = fmaf(a.x, beta, a2.x);
                a.y = fmaf(a.y, beta, a2.y);
                a.z = fmaf(a.z, beta, a2.z);
                a.w = fmaf(a.w, beta, a2.w);
            }
            short4 h, l;
            {
                const float av[4] = {a.x, a.y, a.z, a.w};
                short hh[4], ll[4];
                #pragma unroll
                for (int i = 0; i < 4; ++i) {
                    unsigned short hb = bf16_rne(av[i]);
                    hh[i] = (short)hb;
                    ll[i] = (short)bf16_rne(av[i] - __uint_as_float((unsigned)hb << 16));
                }
                h = make_short4(hh[0], hh[1], hh[2], hh[3]);
                l = make_short4(ll[0], ll[1], ll[2], ll[3]);
            }
            const int kk = sa_k ^ ((m & 7) << 3);
            *(short4*)&AsH[m][kk] = h;
            *(short4*)&AsL[m][kk] = l;
        }
        // ---- stage B tile 64x64 transposed into [n][k], split, swizzled ----
        #pragma unroll
        for (int p = 0; p < 4; ++p) {
            short hh[4], ll[4];
            #pragma unroll
            for (int i = 0; i < 4; ++i) {
                float b = B[(size_t)(k0 + sb_k0 + (p << 2) + i) * C_DIM + n0 + sb_n];
                unsigned short hb = bf16_rne(b);
                hh[i] = (short)hb;
                ll[i] = (short)bf16_rne(b - __uint_as_float((unsigned)hb << 16));
            }
            const int kk = ((sb_k0 + (p << 2))) ^ ((sb_n & 7) << 3);
            *(short4*)&BsH[sb_n][kk] = make_short4(hh[0], hh[1], hh[2], hh[3]);
            *(short4*)&BsL[sb_n][kk] = make_short4(ll[0], ll[1], ll[2], ll[3]);
        }
        __syncthreads();

        // ---- MFMA inner: 2 k-frags x (4m x 2n) x 3 splits ----
        #pragma unroll
        for (int kf = 0; kf < 2; ++kf) {
            const int kk = (((kf << 2) + q) ^ (fr & 7)) << 3;   // swizzled elem offset
            bf16x8 aH[4], aL[4], bH[2], bL[2];
            #pragma unroll
            for (int fm = 0; fm < 4; ++fm) {
                const int row = wm + (fm << 4) + fr;
                aH[fm] = *(const bf16x8*)&AsH[row][kk];
                aL[fm] = *(const bf16x8*)&AsL[row][kk];
            }
            #pragma unroll
            for (int fn = 0; fn < 2; ++fn) {
                const int row = wn + (fn << 4) + fr;
                bH[fn] = *(const bf16x8*)&BsH[row][kk];
                bL[fn] = *(const bf16x8*)&BsL[row][kk];
            }
            #pragma unroll
            for (int fm = 0; fm < 4; ++fm)
                #pragma unroll
                for (int fn = 0; fn < 2; ++fn) {
                    acc[fm][fn] = __builtin_amdgcn_mfma_f32_16x16x32_bf16(aH[fm], bH[fn], acc[fm][fn], 0, 0, 0);
                    acc[fm][fn] = __builtin_amdgcn_mfma_f32_16x16x32_bf16(aH[fm], bL[fn], acc[fm][fn], 0, 0, 0);
                    acc[fm][fn] = __builtin_amdgcn_mfma_f32_16x16x32_bf16(aL[fm], bH[fn], acc[fm][fn], 0, 0, 0);
                }
        }
        __syncthreads();
    }

    // ---- epilogue: bias + relu (+resid), C/D layout col=lane&15, row=q*4+r ----
    #pragma unroll
    for (int fn = 0; fn < 2; ++fn) {
        const int col = n0 + wn + (fn << 4) + fr;
        const float bb = bias[col];
        #pragma unroll
        for (int fm = 0; fm < 4; ++fm) {
            #pragma unroll
            for (int r = 0; r < 4; ++r) {
                const int row = m0 + wm + (fm << 4) + (q << 2) + r;
                float v = acc[fm][fn][r] + bb;
                if (RELU) v = fmaxf(v, 0.f);
                if (RESID) v += resid[(size_t)row * C_DIM + col];
                Cout[(size_t)row * C_DIM + col] = v;
            }
        }
    }
}

// ---------------- per-edge: common-neighbor gather + xi*xj ----------------
__global__ __launch_bounds__(256) void k_edges(
    const unsigned long long* __restrict__ bits, const float* __restrict__ x,
    const float* __restrict__ H, const int* __restrict__ tar,
    float* __restrict__ xcn, float* __restrict__ xij)
{
    __shared__ int s_cnt;
    __shared__ int s_idx[256];     // max common neighbors << 256 (max degree ~65)
    const int e = blockIdx.x;
    const int i = tar[e];
    const int j = tar[E_EDGES + e];
    const int t = threadIdx.x;
    if (t == 0) s_cnt = 0;
    __syncthreads();
    const int W = N_NODES / 64;    // 128 words per row
    if (t < W) {
        unsigned long long m = bits[(size_t)i * W + t] & bits[(size_t)j * W + t];
        while (m) {
            int b = __builtin_ctzll(m);
            int slot = atomicAdd(&s_cnt, 1);
            if (slot < 256) s_idx[slot] = (t << 6) + b;
            m &= m - 1;
        }
    }
    __syncthreads();
    const int cnt = min(s_cnt, 256);
    float acc = 0.f;
    for (int q = 0; q < cnt; ++q)
        acc += H[(size_t)s_idx[q] * C_DIM + t];
    xcn[(size_t)e * C_DIM + t] = acc;
    xij[(size_t)e * C_DIM + t] = x[(size_t)i * C_DIM + t] * x[(size_t)j * C_DIM + t];
}

// ---------------- final GEMV: out[e] = L1[e,:] @ w2 + b2 ----------------
__global__ __launch_bounds__(256) void k_gemv_out(const float* __restrict__ L1,
                                                  const float* __restrict__ w2,
                                                  const float* __restrict__ b2,
                                                  float* __restrict__ out) {
    const int gw   = (int)((blockIdx.x * blockDim.x + threadIdx.x) >> 6);
    const int lane = threadIdx.x & 63;
    if (gw >= E_EDGES) return;
    const float* row = L1 + (size_t)gw * C_DIM;
    float s = 0.f;
    #pragma unroll
    for (int c = 0; c < C_DIM; c += 64) s += row[c + lane] * w2[c + lane];
    #pragma unroll
    for (int off = 32; off; off >>= 1) s += __shfl_down(s, off);
    if (lane == 0) out[gw] = s + b2[0];
}

extern "C" void kernel_launch(void* const* d_in, const int* in_sizes, int n_in,
                              void* d_out, int out_size, void* d_ws, size_t ws_size,
                              hipStream_t stream) {
    const float* x       = (const float*)d_in[0];
    const float* adj     = (const float*)d_in[1];
    const int*   tar_ei  = (const int*)  d_in[2];
    const float* xlin_w1 = (const float*)d_in[3];
    const float* xlin_b1 = (const float*)d_in[4];
    const float* xlin_w2 = (const float*)d_in[5];
    const float* xlin_b2 = (const float*)d_in[6];
    const float* xcn_w1  = (const float*)d_in[7];
    const float* xcn_b1  = (const float*)d_in[8];
    const float* xcn_w2  = (const float*)d_in[9];
    const float* xcn_b2  = (const float*)d_in[10];
    const float* xij_w   = (const float*)d_in[11];
    const float* xij_b   = (const float*)d_in[12];
    const float* lin_w1  = (const float*)d_in[13];
    const float* lin_b1  = (const float*)d_in[14];
    const float* lin_w2  = (const float*)d_in[15];
    const float* lin_b2  = (const float*)d_in[16];
    const float* beta    = (const float*)d_in[17];
    float* out = (float*)d_out;

    char* ws = (char*)d_ws;
    const size_t SZ = (size_t)N_NODES * C_DIM * sizeof(float);   // 8 MB
    unsigned long long* bits = (unsigned long long*)(ws);        // 8 MB
    float* B1 = (float*)(ws + 1 * SZ);   // tmp
    float* B2 = (float*)(ws + 2 * SZ);   // H
    float* B3 = (float*)(ws + 3 * SZ);   // xcn_raw -> XCN2
    float* B4 = (float*)(ws + 4 * SZ);   // xij_in
    float* B5 = (float*)(ws + 5 * SZ);   // XIJ

    const dim3 gG(N_NODES / 128, C_DIM / 64);   // (64, 4)
    const dim3 b256(256);

    hipLaunchKernelGGL(k_bitmask, dim3(2048), b256, 0, stream, adj, bits);
    hipLaunchKernelGGL((k_gemm_mfma<false, false, true>), gG, b256, 0, stream,
                       x,  nullptr, nullptr, xlin_w1, xlin_b1, nullptr, B1);
    hipLaunchKernelGGL((k_gemm_mfma<false, true,  true>), gG, b256, 0, stream,
                       B1, nullptr, nullptr, xlin_w2, xlin_b2, x,      B2);
    hipLaunchKernelGGL(k_edges, dim3(E_EDGES), b256, 0, stream,
                       bits, x, B2, tar_ei, B3, B4);
    hipLaunchKernelGGL((k_gemm_mfma<false, false, true>), gG, b256, 0, stream,
                       B4, nullptr, nullptr, xij_w,  xij_b,  nullptr, B5);
    hipLaunchKernelGGL((k_gemm_mfma<false, false, true>), gG, b256, 0, stream,
                       B3, nullptr, nullptr, xcn_w1, xcn_b1, nullptr, B1);
    hipLaunchKernelGGL((k_gemm_mfma<false, false, true>), gG, b256, 0, stream,
                       B1, nullptr, nullptr, xcn_w2, xcn_b2, nullptr, B3);
    hipLaunchKernelGGL((k_gemm_mfma<true,  false, true>), gG, b256, 0, stream,
                       B3, B5, beta, lin_w1, lin_b1, nullptr, B1);
    hipLaunchKernelGGL(k_gemv_out, dim3(E_EDGES / 4), b256, 0, stream,
                       B1, lin_w2, lin_b2, out);
}

// Round 4
// 158.033 us; speedup vs baseline: 1.4996x; 1.4996x over previous
//
#include <hip/hip_runtime.h>
#include <cstdint>
#include <cstddef>

// CNLinkPredictor on MI355X — round 4: split-once, GEMMs consume bf16 planes.
//
//   k_bitmask : adj (256 MB) -> bit rows [N][128] u64        (~42 us HBM floor)
//   k_split_w : 6 weights -> transposed [n][k] hi/lo bf16 planes (once)
//   k_split_x : x -> hi/lo planes
//   g1: T1(split) = relu(x @ w1 + b)            [A=xsplit,  out split]
//   g2: H(f32)    = x + relu(T1 @ w2 + b)       [resid=x,   out f32]
//   edges: xcn(split), xij(split) from bits/H/x
//   g3: XIJ(f32)  = relu(xij @ xij_w + b)
//   g4: T2(split) = relu(xcn @ w1 + b)
//   g5: z(split)  = relu(T2 @ w2 + b)*beta + XIJ   [epilogue fuse]
//   g6: L1(f32)   = relu(z @ lin_w1 + b)
//   gemv: out = L1 @ lin_w2 + b2
//
// GEMM: BM=BN=BK=64, 4 waves (32x32 each), mfma_f32_16x16x32_bf16,
// 3 MFMAs per frag pair (HH+HL+LH). No fp32->bf16 conversion inside the
// GEMM: inputs are pre-split planes, staging is pure 16B load + swizzled
// ds_write_b128 (chunk swizzle c ^= row&7 -> conflict-free frag reads).

#define C_DIM   256
#define N_NODES 8192
#define E_EDGES 8192

typedef short bf16x8 __attribute__((ext_vector_type(8)));
typedef float f32x4  __attribute__((ext_vector_type(4)));

struct WPtrs { const float* p[6]; };

__device__ __forceinline__ unsigned short bf16_rne(float a) {
    unsigned u = __float_as_uint(a);
    u += 0x7FFFu + ((u >> 16) & 1u);
    return (unsigned short)(u >> 16);
}
__device__ __forceinline__ void split2(float v, short& h, short& l) {
    unsigned short hb = bf16_rne(v);
    h = (short)hb;
    l = (short)bf16_rne(v - __uint_as_float((unsigned)hb << 16));
}

// ---------------- adjacency -> bitmask ----------------
__global__ __launch_bounds__(256) void k_bitmask(const float* __restrict__ adj,
                                                 unsigned long long* __restrict__ bits) {
    const long long TOTAL = (long long)N_NODES * N_NODES / 64;  // 1M words
    const int  lane = threadIdx.x & 63;
    long long wid = (((long long)blockIdx.x * blockDim.x) + threadIdx.x) >> 6;
    long long nw  = ((long long)gridDim.x * blockDim.x) >> 6;
    for (long long w = wid; w < TOTAL; w += nw) {
        float v = adj[(w << 6) + lane];
        unsigned long long m = __ballot(v > 0.5f);
        if (lane == 0) bits[w] = m;
    }
}

// ---------------- weights: transpose + split (once) ----------------
// out: WT[g][n][k] hi/lo planes, g in 0..5
__global__ __launch_bounds__(256) void k_split_w(WPtrs wp, short* __restrict__ WTH,
                                                 short* __restrict__ WTL) {
    __shared__ float tile[64][65];
    const int g   = blockIdx.y;
    const int tk0 = (blockIdx.x >> 2) << 6;
    const int tn0 = (blockIdx.x & 3) << 6;
    const float* w = wp.p[g];
    const int t = threadIdx.x;
    #pragma unroll
    for (int p = 0; p < 16; ++p) {
        const int r = (p << 2) + (t >> 6);
        tile[r][t & 63] = w[(size_t)(tk0 + r) * C_DIM + tn0 + (t & 63)];
    }
    __syncthreads();
    const int n   = t >> 2;
    const int c16 = (t & 3) << 4;
    const size_t base = (size_t)g * 65536 + (size_t)(tn0 + n) * C_DIM + tk0 + c16;
    #pragma unroll
    for (int i = 0; i < 16; i += 4) {
        short h0, l0, h1, l1, h2, l2, h3, l3;
        split2(tile[c16 + i + 0][n], h0, l0);
        split2(tile[c16 + i + 1][n], h1, l1);
        split2(tile[c16 + i + 2][n], h2, l2);
        split2(tile[c16 + i + 3][n], h3, l3);
        *(short4*)&WTH[base + i] = make_short4(h0, h1, h2, h3);
        *(short4*)&WTL[base + i] = make_short4(l0, l1, l2, l3);
    }
}

// ---------------- x -> hi/lo planes ----------------
__global__ __launch_bounds__(256) void k_split_x(const float* __restrict__ x,
                                                 short* __restrict__ xH,
                                                 short* __restrict__ xL) {
    const int TOT = N_NODES * C_DIM / 4;
    for (int idx = blockIdx.x * blockDim.x + threadIdx.x; idx < TOT;
         idx += gridDim.x * blockDim.x) {
        float4 a = ((const float4*)x)[idx];
        short h0, l0, h1, l1, h2, l2, h3, l3;
        split2(a.x, h0, l0); split2(a.y, h1, l1);
        split2(a.z, h2, l2); split2(a.w, h3, l3);
        ((short4*)xH)[idx] = make_short4(h0, h1, h2, h3);
        ((short4*)xL)[idx] = make_short4(l0, l1, l2, l3);
    }
}

// ---------------- split-bf16 MFMA GEMM (pre-split inputs) ----------------
// OUT_MODE: 0 = fp32, 1 = split planes, 2 = split planes of (relu*beta + aux)
// RESID: add aux (fp32) after relu (OUT_MODE 0).
template<int OUT_MODE, bool RESID, bool RELU>
__global__ __launch_bounds__(256, 2) void k_gemm_sb(
    const short* __restrict__ AH, const short* __restrict__ AL,
    const short* __restrict__ BTH, const short* __restrict__ BTL,
    const float* __restrict__ bias, const float* __restrict__ aux,
    const float* __restrict__ betap,
    float* __restrict__ OutF, short* __restrict__ OutH, short* __restrict__ OutL)
{
    __shared__ short AsH[64][64];
    __shared__ short AsL[64][64];
    __shared__ short BsH[64][64];   // [n][k]
    __shared__ short BsL[64][64];

    const int t    = threadIdx.x;
    const int lane = t & 63;
    const int w    = t >> 6;
    const int m0   = blockIdx.x * 64;
    const int n0   = blockIdx.y * 64;
    const int wm   = (w >> 1) * 32;
    const int wn   = (w & 1) * 32;
    const int fr   = lane & 15;
    const int q    = lane >> 4;

    const float beta = (OUT_MODE == 2) ? betap[0] : 0.f;

    f32x4 acc[2][2];
    #pragma unroll
    for (int i = 0; i < 2; ++i)
        #pragma unroll
        for (int j = 0; j < 2; ++j)
            #pragma unroll
            for (int r = 0; r < 4; ++r) acc[i][j][r] = 0.f;

    for (int k0 = 0; k0 < C_DIM; k0 += 64) {
        // stage: 16B vector loads -> swizzled ds_write_b128 (chunk ^= row&7)
        #pragma unroll
        for (int p = 0; p < 2; ++p) {
            const int idx = t + (p << 8);
            const int row = idx >> 3;
            const int c8  = (idx & 7) << 3;
            const int sw  = c8 ^ ((row & 7) << 3);
            const size_t ga = (size_t)(m0 + row) * C_DIM + k0 + c8;
            const size_t gb = (size_t)(n0 + row) * C_DIM + k0 + c8;
            *(uint4*)&AsH[row][sw] = *(const uint4*)&AH[ga];
            *(uint4*)&AsL[row][sw] = *(const uint4*)&AL[ga];
            *(uint4*)&BsH[row][sw] = *(const uint4*)&BTH[gb];
            *(uint4*)&BsL[row][sw] = *(const uint4*)&BTL[gb];
        }
        __syncthreads();

        #pragma unroll
        for (int kf = 0; kf < 2; ++kf) {
            const int cc = (((kf << 2) + q) ^ (fr & 7)) << 3;
            bf16x8 aH[2], aL[2], bH[2], bL[2];
            #pragma unroll
            for (int fm = 0; fm < 2; ++fm) {
                const int row = wm + (fm << 4) + fr;
                aH[fm] = *(const bf16x8*)&AsH[row][cc];
                aL[fm] = *(const bf16x8*)&AsL[row][cc];
            }
            #pragma unroll
            for (int fn = 0; fn < 2; ++fn) {
                const int row = wn + (fn << 4) + fr;
                bH[fn] = *(const bf16x8*)&BsH[row][cc];
                bL[fn] = *(const bf16x8*)&BsL[row][cc];
            }
            #pragma unroll
            for (int fm = 0; fm < 2; ++fm)
                #pragma unroll
                for (int fn = 0; fn < 2; ++fn) {
                    acc[fm][fn] = __builtin_amdgcn_mfma_f32_16x16x32_bf16(aH[fm], bH[fn], acc[fm][fn], 0, 0, 0);
                    acc[fm][fn] = __builtin_amdgcn_mfma_f32_16x16x32_bf16(aH[fm], bL[fn], acc[fm][fn], 0, 0, 0);
                    acc[fm][fn] = __builtin_amdgcn_mfma_f32_16x16x32_bf16(aL[fm], bH[fn], acc[fm][fn], 0, 0, 0);
                }
        }
        __syncthreads();
    }

    // epilogue: C/D layout col = lane&15, row = q*4 + r
    #pragma unroll
    for (int fn = 0; fn < 2; ++fn) {
        const int col = n0 + wn + (fn << 4) + fr;
        const float bb = bias[col];
        #pragma unroll
        for (int fm = 0; fm < 2; ++fm) {
            #pragma unroll
            for (int r = 0; r < 4; ++r) {
                const int row = m0 + wm + (fm << 4) + (q << 2) + r;
                const size_t o = (size_t)row * C_DIM + col;
                float v = acc[fm][fn][r] + bb;
                if (RELU) v = fmaxf(v, 0.f);
                if (RESID) v += aux[o];
                if (OUT_MODE == 2) v = v * beta + aux[o];
                if (OUT_MODE == 0) {
                    OutF[o] = v;
                } else {
                    short h, l;
                    split2(v, h, l);
                    OutH[o] = h;
                    OutL[o] = l;
                }
            }
        }
    }
}

// ---------------- per-edge: CN gather + xi*xj (split outputs) ----------------
__global__ __launch_bounds__(256) void k_edges(
    const unsigned long long* __restrict__ bits, const float* __restrict__ x,
    const float* __restrict__ H, const int* __restrict__ tar,
    short* __restrict__ xcnH, short* __restrict__ xcnL,
    short* __restrict__ xijH, short* __restrict__ xijL)
{
    __shared__ int s_cnt;
    __shared__ int s_idx[256];
    const int e = blockIdx.x;
    const int i = tar[e];
    const int j = tar[E_EDGES + e];
    const int t = threadIdx.x;
    if (t == 0) s_cnt = 0;
    __syncthreads();
    const int W = N_NODES / 64;
    if (t < W) {
        unsigned long long m = bits[(size_t)i * W + t] & bits[(size_t)j * W + t];
        while (m) {
            int b = __builtin_ctzll(m);
            int slot = atomicAdd(&s_cnt, 1);
            if (slot < 256) s_idx[slot] = (t << 6) + b;
            m &= m - 1;
        }
    }
    __syncthreads();
    const int cnt = min(s_cnt, 256);
    float acc = 0.f;
    for (int q = 0; q < cnt; ++q)
        acc += H[(size_t)s_idx[q] * C_DIM + t];
    const size_t o = (size_t)e * C_DIM + t;
    short h, l;
    split2(acc, h, l);
    xcnH[o] = h; xcnL[o] = l;
    split2(x[(size_t)i * C_DIM + t] * x[(size_t)j * C_DIM + t], h, l);
    xijH[o] = h; xijL[o] = l;
}

// ---------------- final GEMV ----------------
__global__ __launch_bounds__(256) void k_gemv_out(const float* __restrict__ L1,
                                                  const float* __restrict__ w2,
                                                  const float* __restrict__ b2,
                                                  float* __restrict__ out) {
    const int gw   = (int)((blockIdx.x * blockDim.x + threadIdx.x) >> 6);
    const int lane = threadIdx.x & 63;
    if (gw >= E_EDGES) return;
    const float* row = L1 + (size_t)gw * C_DIM;
    float s = 0.f;
    #pragma unroll
    for (int c = 0; c < C_DIM; c += 64) s += row[c + lane] * w2[c + lane];
    #pragma unroll
    for (int off = 32; off; off >>= 1) s += __shfl_down(s, off);
    if (lane == 0) out[gw] = s + b2[0];
}

extern "C" void kernel_launch(void* const* d_in, const int* in_sizes, int n_in,
                              void* d_out, int out_size, void* d_ws, size_t ws_size,
                              hipStream_t stream) {
    const float* x       = (const float*)d_in[0];
    const float* adj     = (const float*)d_in[1];
    const int*   tar_ei  = (const int*)  d_in[2];
    const float* xlin_w1 = (const float*)d_in[3];
    const float* xlin_b1 = (const float*)d_in[4];
    const float* xlin_w2 = (const float*)d_in[5];
    const float* xlin_b2 = (const float*)d_in[6];
    const float* xcn_w1  = (const float*)d_in[7];
    const float* xcn_b1  = (const float*)d_in[8];
    const float* xcn_w2  = (const float*)d_in[9];
    const float* xcn_b2  = (const float*)d_in[10];
    const float* xij_w   = (const float*)d_in[11];
    const float* xij_b   = (const float*)d_in[12];
    const float* lin_w1  = (const float*)d_in[13];
    const float* lin_b1  = (const float*)d_in[14];
    const float* lin_w2  = (const float*)d_in[15];
    const float* lin_b2  = (const float*)d_in[16];
    const float* beta    = (const float*)d_in[17];
    float* out = (float*)d_out;

    char* ws = (char*)d_ws;
    const size_t MB = 1024 * 1024;
    unsigned long long* bits = (unsigned long long*)(ws);      // 8 MB
    short* xH   = (short*)(ws +  8 * MB);   // 4 MB each plane
    short* xL   = (short*)(ws + 12 * MB);
    short* T1H  = (short*)(ws + 16 * MB);
    short* T1L  = (short*)(ws + 20 * MB);
    float* Hbuf = (float*)(ws + 24 * MB);   // 8 MB
    short* xcnH = (short*)(ws + 32 * MB);
    short* xcnL = (short*)(ws + 36 * MB);
    short* xijH = (short*)(ws + 40 * MB);
    short* xijL = (short*)(ws + 44 * MB);
    float* XIJ  = (float*)(ws + 48 * MB);   // 8 MB
    short* T2H  = (short*)(ws + 56 * MB);
    short* T2L  = (short*)(ws + 60 * MB);
    short* zH   = (short*)(ws + 64 * MB);
    short* zL   = (short*)(ws + 68 * MB);
    float* L1   = (float*)(ws + 72 * MB);   // 8 MB
    short* WTH  = (short*)(ws + 80 * MB);   // 6*128KB
    short* WTL  = (short*)(ws + 81 * MB);

    WPtrs wp;
    wp.p[0] = xlin_w1; wp.p[1] = xlin_w2; wp.p[2] = xij_w;
    wp.p[3] = xcn_w1;  wp.p[4] = xcn_w2;  wp.p[5] = lin_w1;
    const int WSZ = 65536;

    const dim3 gG(N_NODES / 64, C_DIM / 64);   // (128, 4) = 512 blocks
    const dim3 b256(256);

    hipLaunchKernelGGL(k_bitmask, dim3(2048), b256, 0, stream, adj, bits);
    hipLaunchKernelGGL(k_split_w, dim3(16, 6), b256, 0, stream, wp, WTH, WTL);
    hipLaunchKernelGGL(k_split_x, dim3(2048), b256, 0, stream, x, xH, xL);
    // g1: T1 = relu(x@w1+b)  -> split
    hipLaunchKernelGGL((k_gemm_sb<1, false, true>), gG, b256, 0, stream,
                       xH, xL, WTH + 0 * WSZ, WTL + 0 * WSZ, xlin_b1,
                       nullptr, nullptr, nullptr, T1H, T1L);
    // g2: H = x + relu(T1@w2+b) -> fp32
    hipLaunchKernelGGL((k_gemm_sb<0, true, true>), gG, b256, 0, stream,
                       T1H, T1L, WTH + 1 * WSZ, WTL + 1 * WSZ, xlin_b2,
                       x, nullptr, Hbuf, nullptr, nullptr);
    hipLaunchKernelGGL(k_edges, dim3(E_EDGES), b256, 0, stream,
                       bits, x, Hbuf, tar_ei, xcnH, xcnL, xijH, xijL);
    // g3: XIJ = relu(xij@xij_w+b) -> fp32
    hipLaunchKernelGGL((k_gemm_sb<0, false, true>), gG, b256, 0, stream,
                       xijH, xijL, WTH + 2 * WSZ, WTL + 2 * WSZ, xij_b,
                       nullptr, nullptr, XIJ, nullptr, nullptr);
    // g4: T2 = relu(xcn@w1+b) -> split
    hipLaunchKernelGGL((k_gemm_sb<1, false, true>), gG, b256, 0, stream,
                       xcnH, xcnL, WTH + 3 * WSZ, WTL + 3 * WSZ, xcn_b1,
                       nullptr, nullptr, nullptr, T2H, T2L);
    // g5: z = relu(T2@w2+b)*beta + XIJ -> split
    hipLaunchKernelGGL((k_gemm_sb<2, false, true>), gG, b256, 0, stream,
                       T2H, T2L, WTH + 4 * WSZ, WTL + 4 * WSZ, xcn_b2,
                       XIJ, beta, nullptr, zH, zL);
    // g6: L1 = relu(z@lin_w1+b) -> fp32
    hipLaunchKernelGGL((k_gemm_sb<0, false, true>), gG, b256, 0, stream,
                       zH, zL, WTH + 5 * WSZ, WTL + 5 * WSZ, lin_b1,
                       nullptr, nullptr, L1, nullptr, nullptr);
    hipLaunchKernelGGL(k_gemv_out, dim3(E_EDGES / 4), b256, 0, stream,
                       L1, lin_w2, lin_b2, out);
}

// Round 5
// 146.664 us; speedup vs baseline: 1.6159x; 1.0775x over previous
//
#include <hip/hip_runtime.h>
#include <cstdint>
#include <cstddef>

// CNLinkPredictor on MI355X — round 5: fused MLP chains, frag-major weights.
//
//   k_bitmask : adj (256 MB) -> bit rows [N][128] u64        (~42 us HBM floor)
//   k_split_wf: 6 weights -> frag-major split bf16 planes (once, L2-resident)
//   k_fused_x : per 32-row block: x ->(LDS) relu(x@w1+b) -> H = x + relu(..@w2+b)
//   k_edges   : bits -> xcn (CN gather over H), xij = xi*xj   (split planes)
//   k_fused_e : per 32-row block: XIJ=relu(xij@wij+b) (LDS f32);
//               T2=relu(xcn@w1+b); z=relu(T2@w2+b)*beta+XIJ; L1=relu(z@wl1+b);
//               out = L1@w2+b2 fused into epilogue (shfl reduce + LDS atomic).
//
// Layer: split-bf16 (hi+lo, 3 MFMAs HH+HL+LH), mfma_f32_16x16x32_bf16,
// 8 waves, wave = 32 rows x 32 cols (2 m-frags x 2 n-frags), K=256 (8 kf).
// Activations in LDS split planes [32][256], chunk-XOR swizzle c^=(row&7)
// -> conflict-free ds_read_b128 A-frags. Weights read per-frag as one
// coalesced 16B global load/lane (frag-major layout), no LDS, no barriers
// inside the K-loop.

#define C_DIM   256
#define N_NODES 8192
#define E_EDGES 8192

typedef short bf16x8 __attribute__((ext_vector_type(8)));
typedef float f32x4  __attribute__((ext_vector_type(4)));

struct WPtrs { const float* p[6]; };

__device__ __forceinline__ unsigned short bf16_rne(float a) {
    unsigned u = __float_as_uint(a);
    u += 0x7FFFu + ((u >> 16) & 1u);
    return (unsigned short)(u >> 16);
}
__device__ __forceinline__ void split2(float v, short& h, short& l) {
    unsigned short hb = bf16_rne(v);
    h = (short)hb;
    l = (short)bf16_rne(v - __uint_as_float((unsigned)hb << 16));
}

// ---------------- adjacency -> bitmask ----------------
__global__ __launch_bounds__(256) void k_bitmask(const float* __restrict__ adj,
                                                 unsigned long long* __restrict__ bits) {
    const long long TOTAL = (long long)N_NODES * N_NODES / 64;
    const int  lane = threadIdx.x & 63;
    long long wid = (((long long)blockIdx.x * blockDim.x) + threadIdx.x) >> 6;
    long long nw  = ((long long)gridDim.x * blockDim.x) >> 6;
    for (long long w = wid; w < TOTAL; w += nw) {
        float v = adj[(w << 6) + lane];
        unsigned long long m = __ballot(v > 0.5f);
        if (lane == 0) bits[w] = m;
    }
}

// ---------------- weights -> frag-major split planes ----------------
// For weight g, frag (kf,nf), lane, elem e:  value = W[kf*32+(lane>>4)*8+e][nf*16+(lane&15)]
// stored at WF[g*65536 + ((kf*16+nf)*64+lane)*8 + e].
__global__ __launch_bounds__(256) void k_split_wf(WPtrs wp, short* __restrict__ WFH,
                                                  short* __restrict__ WFL) {
    __shared__ float tile[32][257];
    const int kf = blockIdx.x;    // 0..7
    const int g  = blockIdx.y;    // 0..5
    const float* W = wp.p[g];
    const int t = threadIdx.x;
    #pragma unroll
    for (int p = 0; p < 8; ++p) {
        int s = t + (p << 8);                 // 2048 float4 slots
        int row = s >> 6, c4 = s & 63;
        float4 v = *(const float4*)&W[(size_t)(kf * 32 + row) * C_DIM + (c4 << 2)];
        tile[row][(c4 << 2) + 0] = v.x; tile[row][(c4 << 2) + 1] = v.y;
        tile[row][(c4 << 2) + 2] = v.z; tile[row][(c4 << 2) + 3] = v.w;
    }
    __syncthreads();
    #pragma unroll
    for (int p = 0; p < 4; ++p) {
        int s = t + (p << 8);                 // 1024 (nf,lane) slots
        int nf = s >> 6, lane = s & 63;
        int q = lane >> 4, fr = lane & 15;
        short h[8], l[8];
        #pragma unroll
        for (int e = 0; e < 8; ++e)
            split2(tile[q * 8 + e][nf * 16 + fr], h[e], l[e]);
        int dst = (g << 16) + (((kf * 16 + nf) << 6) + lane) * 8;
        *(short4*)&WFH[dst]     = make_short4(h[0], h[1], h[2], h[3]);
        *(short4*)&WFH[dst + 4] = make_short4(h[4], h[5], h[6], h[7]);
        *(short4*)&WFL[dst]     = make_short4(l[0], l[1], l[2], l[3]);
        *(short4*)&WFL[dst + 4] = make_short4(l[4], l[5], l[6], l[7]);
    }
}

// ---------------- one split-bf16 layer: OUT = relu(IN @ W + b) [mode-variant] ----
// MODE 0: split -> POH/POL      MODE 1: v=v*beta+FO[r][c], split -> POH/POL
// MODE 2: FO[r][c]=v            MODE 3: Hg[m0+r][c] = v + xres[m0+r][c]
// MODE 4: gemv: out32[row] += sum_col v*w2[col]
template<int MODE>
__device__ __forceinline__ void layer_sb(
    const short (*INH)[C_DIM], const short (*INL)[C_DIM],
    const short* __restrict__ WH, const short* __restrict__ WL,
    const float* __restrict__ bias,
    short (*POH)[C_DIM], short (*POL)[C_DIM], float (*FO)[C_DIM],
    float* __restrict__ Hg, const float* __restrict__ xres, int m0,
    float beta, const float* __restrict__ w2, float* __restrict__ out32)
{
    const int t = threadIdx.x, lane = t & 63, wq = t >> 6;   // 8 waves
    const int fr = lane & 15, q = lane >> 4;
    f32x4 acc[2][2];
    #pragma unroll
    for (int i = 0; i < 2; ++i)
        #pragma unroll
        for (int j = 0; j < 2; ++j)
            #pragma unroll
            for (int r = 0; r < 4; ++r) acc[i][j][r] = 0.f;

    #pragma unroll 2
    for (int kf = 0; kf < 8; ++kf) {
        bf16x8 aH[2], aL[2];
        #pragma unroll
        for (int mf = 0; mf < 2; ++mf) {
            const int row = mf * 16 + fr;
            const int cc = (((kf << 2) + q) ^ (row & 7)) << 3;
            aH[mf] = *(const bf16x8*)&INH[row][cc];
            aL[mf] = *(const bf16x8*)&INL[row][cc];
        }
        #pragma unroll
        for (int nl = 0; nl < 2; ++nl) {
            const int nf = wq * 2 + nl;
            const int wo = (((kf << 4) + nf) * 64 + lane) * 8;
            bf16x8 bH = *(const bf16x8*)&WH[wo];
            bf16x8 bL = *(const bf16x8*)&WL[wo];
            #pragma unroll
            for (int mf = 0; mf < 2; ++mf) {
                acc[mf][nl] = __builtin_amdgcn_mfma_f32_16x16x32_bf16(aH[mf], bH, acc[mf][nl], 0, 0, 0);
                acc[mf][nl] = __builtin_amdgcn_mfma_f32_16x16x32_bf16(aH[mf], bL, acc[mf][nl], 0, 0, 0);
                acc[mf][nl] = __builtin_amdgcn_mfma_f32_16x16x32_bf16(aL[mf], bH, acc[mf][nl], 0, 0, 0);
            }
        }
    }

    float gs[2][4];
    if (MODE == 4) {
        #pragma unroll
        for (int mf = 0; mf < 2; ++mf)
            #pragma unroll
            for (int r = 0; r < 4; ++r) gs[mf][r] = 0.f;
    }
    #pragma unroll
    for (int nl = 0; nl < 2; ++nl) {
        const int col = wq * 32 + nl * 16 + fr;
        const float bb = bias[col];
        const float w2c = (MODE == 4) ? w2[col] : 0.f;
        #pragma unroll
        for (int mf = 0; mf < 2; ++mf)
            #pragma unroll
            for (int r = 0; r < 4; ++r) {
                const int row = mf * 16 + q * 4 + r;
                float v = fmaxf(acc[mf][nl][r] + bb, 0.f);
                if (MODE == 0 || MODE == 1) {
                    if (MODE == 1) v = v * beta + FO[row][col];
                    short h, l;
                    split2(v, h, l);
                    const int cw = (((col >> 3) ^ (row & 7)) << 3) + (col & 7);
                    POH[row][cw] = h;
                    POL[row][cw] = l;
                } else if (MODE == 2) {
                    FO[row][col] = v;
                } else if (MODE == 3) {
                    const size_t o = (size_t)(m0 + row) * C_DIM + col;
                    Hg[o] = v + xres[o];
                } else {
                    gs[mf][r] += v * w2c;
                }
            }
    }
    if (MODE == 4) {
        #pragma unroll
        for (int mf = 0; mf < 2; ++mf)
            #pragma unroll
            for (int r = 0; r < 4; ++r) {
                float s = gs[mf][r];
                s += __shfl_xor(s, 1); s += __shfl_xor(s, 2);
                s += __shfl_xor(s, 4); s += __shfl_xor(s, 8);
                if (fr == 0) atomicAdd(&out32[mf * 16 + q * 4 + r], s);
            }
    }
}

// stage global split planes (row-major [*,256]) -> LDS swizzled planes
__device__ __forceinline__ void stage_planes(const short* __restrict__ GH,
                                             const short* __restrict__ GL, size_t base,
                                             short (*PH)[C_DIM], short (*PL)[C_DIM]) {
    const int t = threadIdx.x;
    #pragma unroll
    for (int p = 0; p < 2; ++p) {
        int s = t + (p << 9);                 // 1024 chunk slots
        int row = s >> 5, c = s & 31;
        int sw = (c ^ (row & 7)) << 3;
        *(uint4*)&PH[row][sw] = *(const uint4*)&GH[base + (size_t)row * C_DIM + (c << 3)];
        *(uint4*)&PL[row][sw] = *(const uint4*)&GL[base + (size_t)row * C_DIM + (c << 3)];
    }
}

// ---------------- fused x-chain: H = x + relu(relu(x@w1+b1)@w2+b2) ----------------
__global__ __launch_bounds__(512, 1) void k_fused_x(
    const float* __restrict__ x, const short* __restrict__ WFH,
    const short* __restrict__ WFL, const float* __restrict__ b1,
    const float* __restrict__ b2, float* __restrict__ Hg)
{
    __shared__ short PH[2][32][C_DIM];
    __shared__ short PL[2][32][C_DIM];
    const int m0 = blockIdx.x << 5;
    const int t = threadIdx.x;
    #pragma unroll
    for (int p = 0; p < 4; ++p) {
        int s = t + (p << 9);                 // 2048 float4 slots
        int row = s >> 6, c4 = s & 63;
        float4 v = *(const float4*)&x[(size_t)(m0 + row) * C_DIM + (c4 << 2)];
        short h0, l0, h1, l1, h2, l2, h3, l3;
        split2(v.x, h0, l0); split2(v.y, h1, l1);
        split2(v.z, h2, l2); split2(v.w, h3, l3);
        int sw = (((c4 >> 1) ^ (row & 7)) << 3) + ((c4 & 1) << 2);
        *(short4*)&PH[0][row][sw] = make_short4(h0, h1, h2, h3);
        *(short4*)&PL[0][row][sw] = make_short4(l0, l1, l2, l3);
    }
    __syncthreads();
    layer_sb<0>(PH[0], PL[0], WFH + 0 * 65536, WFL + 0 * 65536, b1,
                PH[1], PL[1], nullptr, nullptr, nullptr, 0, 0.f, nullptr, nullptr);
    __syncthreads();
    layer_sb<3>(PH[1], PL[1], WFH + 1 * 65536, WFL + 1 * 65536, b2,
                nullptr, nullptr, nullptr, Hg, x, m0, 0.f, nullptr, nullptr);
}

// ---------------- per-edge: CN gather + xi*xj (split outputs) ----------------
__global__ __launch_bounds__(256) void k_edges(
    const unsigned long long* __restrict__ bits, const float* __restrict__ x,
    const float* __restrict__ H, const int* __restrict__ tar,
    short* __restrict__ xcnH, short* __restrict__ xcnL,
    short* __restrict__ xijH, short* __restrict__ xijL)
{
    __shared__ int s_cnt;
    __shared__ int s_idx[256];
    const int e = blockIdx.x;
    const int i = tar[e];
    const int j = tar[E_EDGES + e];
    const int t = threadIdx.x;
    if (t == 0) s_cnt = 0;
    __syncthreads();
    const int W = N_NODES / 64;
    if (t < W) {
        unsigned long long m = bits[(size_t)i * W + t] & bits[(size_t)j * W + t];
        while (m) {
            int b = __builtin_ctzll(m);
            int slot = atomicAdd(&s_cnt, 1);
            if (slot < 256) s_idx[slot] = (t << 6) + b;
            m &= m - 1;
        }
    }
    __syncthreads();
    const int cnt = min(s_cnt, 256);
    float acc = 0.f;
    for (int q = 0; q < cnt; ++q)
        acc += H[(size_t)s_idx[q] * C_DIM + t];
    const size_t o = (size_t)e * C_DIM + t;
    short h, l;
    split2(acc, h, l);
    xcnH[o] = h; xcnL[o] = l;
    split2(x[(size_t)i * C_DIM + t] * x[(size_t)j * C_DIM + t], h, l);
    xijH[o] = h; xijL[o] = l;
}

// ---------------- fused edge-chain: 4 layers + gemv ----------------
__global__ __launch_bounds__(512, 1) void k_fused_e(
    const short* __restrict__ xijH, const short* __restrict__ xijL,
    const short* __restrict__ xcnH, const short* __restrict__ xcnL,
    const short* __restrict__ WFH, const short* __restrict__ WFL,
    const float* __restrict__ bxij, const float* __restrict__ bcn1,
    const float* __restrict__ bcn2, const float* __restrict__ blin1,
    const float* __restrict__ betap, const float* __restrict__ w2,
    const float* __restrict__ b2, float* __restrict__ out)
{
    __shared__ short PH[2][32][C_DIM];
    __shared__ short PL[2][32][C_DIM];
    __shared__ float FO[32][C_DIM];
    __shared__ float out32[32];
    const int m0 = blockIdx.x << 5;
    const int t = threadIdx.x;
    if (t < 32) out32[t] = 0.f;
    const float beta = betap[0];
    const size_t base = (size_t)m0 * C_DIM;

    stage_planes(xijH, xijL, base, PH[0], PL[0]);
    __syncthreads();
    // XIJ = relu(xij @ xij_w + b) -> FO (f32 LDS)
    layer_sb<2>(PH[0], PL[0], WFH + 2 * 65536, WFL + 2 * 65536, bxij,
                nullptr, nullptr, FO, nullptr, nullptr, 0, 0.f, nullptr, nullptr);
    __syncthreads();
    stage_planes(xcnH, xcnL, base, PH[0], PL[0]);
    __syncthreads();
    // T2 = relu(xcn @ xcn_w1 + b) -> P1
    layer_sb<0>(PH[0], PL[0], WFH + 3 * 65536, WFL + 3 * 65536, bcn1,
                PH[1], PL[1], nullptr, nullptr, nullptr, 0, 0.f, nullptr, nullptr);
    __syncthreads();
    // z = relu(T2 @ xcn_w2 + b)*beta + XIJ -> P0
    layer_sb<1>(PH[1], PL[1], WFH + 4 * 65536, WFL + 4 * 65536, bcn2,
                PH[0], PL[0], FO, nullptr, nullptr, 0, beta, nullptr, nullptr);
    __syncthreads();
    // out = relu(z @ lin_w1 + b) @ w2  (gemv fused)
    layer_sb<4>(PH[0], PL[0], WFH + 5 * 65536, WFL + 5 * 65536, blin1,
                nullptr, nullptr, nullptr, nullptr, nullptr, 0, 0.f, w2, out32);
    __syncthreads();
    if (t < 32) out[m0 + t] = out32[t] + b2[0];
}

extern "C" void kernel_launch(void* const* d_in, const int* in_sizes, int n_in,
                              void* d_out, int out_size, void* d_ws, size_t ws_size,
                              hipStream_t stream) {
    const float* x       = (const float*)d_in[0];
    const float* adj     = (const float*)d_in[1];
    const int*   tar_ei  = (const int*)  d_in[2];
    const float* xlin_w1 = (const float*)d_in[3];
    const float* xlin_b1 = (const float*)d_in[4];
    const float* xlin_w2 = (const float*)d_in[5];
    const float* xlin_b2 = (const float*)d_in[6];
    const float* xcn_w1  = (const float*)d_in[7];
    const float* xcn_b1  = (const float*)d_in[8];
    const float* xcn_w2  = (const float*)d_in[9];
    const float* xcn_b2  = (const float*)d_in[10];
    const float* xij_w   = (const float*)d_in[11];
    const float* xij_b   = (const float*)d_in[12];
    const float* lin_w1  = (const float*)d_in[13];
    const float* lin_b1  = (const float*)d_in[14];
    const float* lin_w2  = (const float*)d_in[15];
    const float* lin_b2  = (const float*)d_in[16];
    const float* beta    = (const float*)d_in[17];
    float* out = (float*)d_out;

    char* ws = (char*)d_ws;
    const size_t MB = 1024 * 1024;
    unsigned long long* bits = (unsigned long long*)(ws);       // 8 MB
    short* WFH  = (short*)(ws +  8 * MB);   // 768 KB (6 x 128 KB)
    short* WFL  = (short*)(ws +  9 * MB);   // 768 KB
    float* Hbuf = (float*)(ws + 10 * MB);   // 8 MB
    short* xcnH = (short*)(ws + 18 * MB);   // 4 MB each
    short* xcnL = (short*)(ws + 22 * MB);
    short* xijH = (short*)(ws + 26 * MB);
    short* xijL = (short*)(ws + 30 * MB);

    WPtrs wp;
    wp.p[0] = xlin_w1; wp.p[1] = xlin_w2; wp.p[2] = xij_w;
    wp.p[3] = xcn_w1;  wp.p[4] = xcn_w2;  wp.p[5] = lin_w1;

    hipLaunchKernelGGL(k_bitmask, dim3(2048), dim3(256), 0, stream, adj, bits);
    hipLaunchKernelGGL(k_split_wf, dim3(8, 6), dim3(256), 0, stream, wp, WFH, WFL);
    hipLaunchKernelGGL(k_fused_x, dim3(N_NODES / 32), dim3(512), 0, stream,
                       x, WFH, WFL, xlin_b1, xlin_b2, Hbuf);
    hipLaunchKernelGGL(k_edges, dim3(E_EDGES), dim3(256), 0, stream,
                       bits, x, Hbuf, tar_ei, xcnH, xcnL, xijH, xijL);
    hipLaunchKernelGGL(k_fused_e, dim3(E_EDGES / 32), dim3(512), 0, stream,
                       xijH, xijL, xcnH, xcnL, WFH, WFL,
                       xij_b, xcn_b1, xcn_b2, lin_b1, beta, lin_w2, lin_b2, out);
}

// Round 6
// 99.547 us; speedup vs baseline: 2.3807x; 1.4733x over previous
//
#include <hip/hip_runtime.h>
#include <cstdint>
#include <cstddef>

// CNLinkPredictor on MI355X — round 6: 3 kernels.
//   k_prep      : blocks 0..47  -> 6 weights to frag-major split planes
//                 blocks 48..   -> adj -> bitmask (vectorized float4, u64/thread)
//   k_fused_x   : x ->(LDS) relu(x@w1+b) -> H = x + relu(..@w2+b)   [32 rows/block]
//   k_fused_edge: per 32-edge block: bit-scan CN + H-gather + xi*xj -> LDS planes;
//                 XIJ layer -> T2 -> z(beta,XIJ) -> L1 -> gemv, all in-LDS.
//
// Layer math: split-bf16 (hi+lo, 3 MFMAs HH+HL+LH), mfma_f32_16x16x32_bf16,
// 8 waves, wave = 32 rows x 32 cols, K=256. Activations in LDS split planes
// [32][256] with chunk-XOR swizzle (c8 ^= row&7) -> conflict-free ds_read_b128.
// Weights frag-major in global (L2-resident), one 16B load/lane/frag, no
// barriers inside K-loop.

#define C_DIM   256
#define N_NODES 8192
#define E_EDGES 8192

typedef short bf16x8 __attribute__((ext_vector_type(8)));
typedef float f32x4  __attribute__((ext_vector_type(4)));

struct WPtrs { const float* p[6]; };

__device__ __forceinline__ unsigned short bf16_rne(float a) {
    unsigned u = __float_as_uint(a);
    u += 0x7FFFu + ((u >> 16) & 1u);
    return (unsigned short)(u >> 16);
}
__device__ __forceinline__ void split2(float v, short& h, short& l) {
    unsigned short hb = bf16_rne(v);
    h = (short)hb;
    l = (short)bf16_rne(v - __uint_as_float((unsigned)hb << 16));
}

// ---------------- prep: weights (blocks 0..47) + bitmask (blocks 48..1071) ----
__global__ __launch_bounds__(256) void k_prep(const float* __restrict__ adj,
                                              unsigned long long* __restrict__ bits,
                                              WPtrs wp, short* __restrict__ WFH,
                                              short* __restrict__ WFL) {
    const int t = threadIdx.x;
    if (blockIdx.x < 48) {
        __shared__ float tile[32][257];
        const int g  = blockIdx.x >> 3;
        const int kf = blockIdx.x & 7;
        const float* W = wp.p[g];
        #pragma unroll
        for (int p = 0; p < 8; ++p) {
            int s = t + (p << 8);
            int row = s >> 6, c4 = s & 63;
            float4 v = *(const float4*)&W[(size_t)(kf * 32 + row) * C_DIM + (c4 << 2)];
            tile[row][(c4 << 2) + 0] = v.x; tile[row][(c4 << 2) + 1] = v.y;
            tile[row][(c4 << 2) + 2] = v.z; tile[row][(c4 << 2) + 3] = v.w;
        }
        __syncthreads();
        #pragma unroll
        for (int p = 0; p < 4; ++p) {
            int s = t + (p << 8);
            int nf = s >> 6, lane = s & 63;
            int q = lane >> 4, fr = lane & 15;
            short h[8], l[8];
            #pragma unroll
            for (int e = 0; e < 8; ++e)
                split2(tile[q * 8 + e][nf * 16 + fr], h[e], l[e]);
            int dst = (g << 16) + (((kf * 16 + nf) << 6) + lane) * 8;
            *(short4*)&WFH[dst]     = make_short4(h[0], h[1], h[2], h[3]);
            *(short4*)&WFH[dst + 4] = make_short4(h[4], h[5], h[6], h[7]);
            *(short4*)&WFL[dst]     = make_short4(l[0], l[1], l[2], l[3]);
            *(short4*)&WFL[dst + 4] = make_short4(l[4], l[5], l[6], l[7]);
        }
    } else {
        // bitmask: one u64 word per thread, 16 x float4 sequential reads
        const int TOTAL = N_NODES * N_NODES / 64;           // 1M words
        const int NT    = 1024 * 256;
        int w = (int)(blockIdx.x - 48) * 256 + t;
        #pragma unroll 1
        for (; w < TOTAL; w += NT) {
            const float4* p = (const float4*)(adj + ((size_t)w << 6));
            unsigned long long m = 0;
            #pragma unroll
            for (int k = 0; k < 16; ++k) {
                float4 v = p[k];
                unsigned nib = (unsigned)(v.x > 0.5f) | ((unsigned)(v.y > 0.5f) << 1) |
                               ((unsigned)(v.z > 0.5f) << 2) | ((unsigned)(v.w > 0.5f) << 3);
                m |= (unsigned long long)nib << (k << 2);
            }
            bits[w] = m;
        }
    }
}

// ---------------- one split-bf16 layer: OUT = relu(IN @ W + b) [mode-variant] ----
// MODE 0: split -> POH/POL      MODE 1: v=v*beta+FO[r][c], split -> POH/POL
// MODE 2: FO[r][c]=v            MODE 3: Hg[m0+r][c] = v + xres[m0+r][c]
// MODE 4: gemv: out32[row] += sum_col v*w2[col]
template<int MODE>
__device__ __forceinline__ void layer_sb(
    const short (*INH)[C_DIM], const short (*INL)[C_DIM],
    const short* __restrict__ WH, const short* __restrict__ WL,
    const float* __restrict__ bias,
    short (*POH)[C_DIM], short (*POL)[C_DIM], float (*FO)[C_DIM],
    float* __restrict__ Hg, const float* __restrict__ xres, int m0,
    float beta, const float* __restrict__ w2, float* __restrict__ out32)
{
    const int t = threadIdx.x, lane = t & 63, wq = t >> 6;   // 8 waves
    const int fr = lane & 15, q = lane >> 4;
    f32x4 acc[2][2];
    #pragma unroll
    for (int i = 0; i < 2; ++i)
        #pragma unroll
        for (int j = 0; j < 2; ++j)
            #pragma unroll
            for (int r = 0; r < 4; ++r) acc[i][j][r] = 0.f;

    #pragma unroll 2
    for (int kf = 0; kf < 8; ++kf) {
        bf16x8 aH[2], aL[2];
        #pragma unroll
        for (int mf = 0; mf < 2; ++mf) {
            const int row = mf * 16 + fr;
            const int cc = (((kf << 2) + q) ^ (row & 7)) << 3;
            aH[mf] = *(const bf16x8*)&INH[row][cc];
            aL[mf] = *(const bf16x8*)&INL[row][cc];
        }
        #pragma unroll
        for (int nl = 0; nl < 2; ++nl) {
            const int nf = wq * 2 + nl;
            const int wo = (((kf << 4) + nf) * 64 + lane) * 8;
            bf16x8 bH = *(const bf16x8*)&WH[wo];
            bf16x8 bL = *(const bf16x8*)&WL[wo];
            #pragma unroll
            for (int mf = 0; mf < 2; ++mf) {
                acc[mf][nl] = __builtin_amdgcn_mfma_f32_16x16x32_bf16(aH[mf], bH, acc[mf][nl], 0, 0, 0);
                acc[mf][nl] = __builtin_amdgcn_mfma_f32_16x16x32_bf16(aH[mf], bL, acc[mf][nl], 0, 0, 0);
                acc[mf][nl] = __builtin_amdgcn_mfma_f32_16x16x32_bf16(aL[mf], bH, acc[mf][nl], 0, 0, 0);
            }
        }
    }

    float gs[2][4];
    if (MODE == 4) {
        #pragma unroll
        for (int mf = 0; mf < 2; ++mf)
            #pragma unroll
            for (int r = 0; r < 4; ++r) gs[mf][r] = 0.f;
    }
    #pragma unroll
    for (int nl = 0; nl < 2; ++nl) {
        const int col = wq * 32 + nl * 16 + fr;
        const float bb = bias[col];
        const float w2c = (MODE == 4) ? w2[col] : 0.f;
        #pragma unroll
        for (int mf = 0; mf < 2; ++mf)
            #pragma unroll
            for (int r = 0; r < 4; ++r) {
                const int row = mf * 16 + q * 4 + r;
                float v = fmaxf(acc[mf][nl][r] + bb, 0.f);
                if (MODE == 0 || MODE == 1) {
                    if (MODE == 1) v = v * beta + FO[row][col];
                    short h, l;
                    split2(v, h, l);
                    const int cw = (((col >> 3) ^ (row & 7)) << 3) + (col & 7);
                    POH[row][cw] = h;
                    POL[row][cw] = l;
                } else if (MODE == 2) {
                    FO[row][col] = v;
                } else if (MODE == 3) {
                    const size_t o = (size_t)(m0 + row) * C_DIM + col;
                    Hg[o] = v + xres[o];
                } else {
                    gs[mf][r] += v * w2c;
                }
            }
    }
    if (MODE == 4) {
        #pragma unroll
        for (int mf = 0; mf < 2; ++mf)
            #pragma unroll
            for (int r = 0; r < 4; ++r) {
                float s = gs[mf][r];
                s += __shfl_xor(s, 1); s += __shfl_xor(s, 2);
                s += __shfl_xor(s, 4); s += __shfl_xor(s, 8);
                if (fr == 0) atomicAdd(&out32[mf * 16 + q * 4 + r], s);
            }
    }
}

// ---------------- fused x-chain: H = x + relu(relu(x@w1+b1)@w2+b2) ----------------
__global__ __launch_bounds__(512, 1) void k_fused_x(
    const float* __restrict__ x, const short* __restrict__ WFH,
    const short* __restrict__ WFL, const float* __restrict__ b1,
    const float* __restrict__ b2, float* __restrict__ Hg)
{
    __shared__ short PH[2][32][C_DIM];
    __shared__ short PL[2][32][C_DIM];
    const int m0 = blockIdx.x << 5;
    const int t = threadIdx.x;
    #pragma unroll
    for (int p = 0; p < 4; ++p) {
        int s = t + (p << 9);
        int row = s >> 6, c4 = s & 63;
        float4 v = *(const float4*)&x[(size_t)(m0 + row) * C_DIM + (c4 << 2)];
        short h0, l0, h1, l1, h2, l2, h3, l3;
        split2(v.x, h0, l0); split2(v.y, h1, l1);
        split2(v.z, h2, l2); split2(v.w, h3, l3);
        int sw = (((c4 >> 1) ^ (row & 7)) << 3) + ((c4 & 1) << 2);
        *(short4*)&PH[0][row][sw] = make_short4(h0, h1, h2, h3);
        *(short4*)&PL[0][row][sw] = make_short4(l0, l1, l2, l3);
    }
    __syncthreads();
    layer_sb<0>(PH[0], PL[0], WFH + 0 * 65536, WFL + 0 * 65536, b1,
                PH[1], PL[1], nullptr, nullptr, nullptr, 0, 0.f, nullptr, nullptr);
    __syncthreads();
    layer_sb<3>(PH[1], PL[1], WFH + 1 * 65536, WFL + 1 * 65536, b2,
                nullptr, nullptr, nullptr, Hg, x, m0, 0.f, nullptr, nullptr);
}

// ---------------- fused edge-chain: scan + gather + 4 layers + gemv ----------------
__global__ __launch_bounds__(512, 1) void k_fused_edge(
    const unsigned long long* __restrict__ bits, const float* __restrict__ x,
    const float* __restrict__ H, const int* __restrict__ tar,
    const short* __restrict__ WFH, const short* __restrict__ WFL,
    const float* __restrict__ bxij, const float* __restrict__ bcn1,
    const float* __restrict__ bcn2, const float* __restrict__ blin1,
    const float* __restrict__ betap, const float* __restrict__ w2,
    const float* __restrict__ b2, float* __restrict__ out)
{
    __shared__ short PH[2][32][C_DIM];
    __shared__ short PL[2][32][C_DIM];
    __shared__ float FO[32][C_DIM];
    __shared__ int   eij2[32][2];
    __shared__ int   cncnt[32];
    __shared__ int   cnlist[32][32];
    __shared__ float out32[32];
    const int e0 = blockIdx.x << 5;
    const int t = threadIdx.x;
    if (t < 32) {
        eij2[t][0] = tar[e0 + t];
        eij2[t][1] = tar[E_EDGES + e0 + t];
        cncnt[t] = 0;
        out32[t] = 0.f;
    }
    __syncthreads();
    // xij staging -> P0 (16 (e,c) pairs per thread)
    #pragma unroll
    for (int p = 0; p < 16; ++p) {
        int idx = (p << 9) + t;
        int e = idx >> 8, c = idx & 255;
        float v = x[(size_t)eij2[e][0] * C_DIM + c] * x[(size_t)eij2[e][1] * C_DIM + c];
        short h, l;
        split2(v, h, l);
        int cw = (((c >> 3) ^ (e & 7)) << 3) + (c & 7);
        PH[0][e][cw] = h;
        PL[0][e][cw] = l;
    }
    // CN bit-scan: 16 threads/edge, 8 u64 words each
    {
        const int le = t >> 4, sub = t & 15;
        const size_t bi = (size_t)eij2[le][0] * 128;
        const size_t bj = (size_t)eij2[le][1] * 128;
        #pragma unroll
        for (int w8 = 0; w8 < 8; ++w8) {
            const int w = (sub << 3) + w8;
            unsigned long long m = bits[bi + w] & bits[bj + w];
            while (m) {
                int b = __builtin_ctzll(m);
                int slot = atomicAdd(&cncnt[le], 1);
                if (slot < 32) cnlist[le][slot] = (w << 6) + b;
                m &= m - 1;
            }
        }
    }
    __syncthreads();
    // CN gather -> P1
    #pragma unroll
    for (int p = 0; p < 16; ++p) {
        int idx = (p << 9) + t;
        int e = idx >> 8, c = idx & 255;
        float acc = 0.f;
        const int cnt = min(cncnt[e], 32);
        for (int q = 0; q < cnt; ++q)
            acc += H[(size_t)cnlist[e][q] * C_DIM + c];
        short h, l;
        split2(acc, h, l);
        int cw = (((c >> 3) ^ (e & 7)) << 3) + (c & 7);
        PH[1][e][cw] = h;
        PL[1][e][cw] = l;
    }
    __syncthreads();
    const float beta = betap[0];
    // XIJ = relu(xij @ xij_w + b) -> FO
    layer_sb<2>(PH[0], PL[0], WFH + 2 * 65536, WFL + 2 * 65536, bxij,
                nullptr, nullptr, FO, nullptr, nullptr, 0, 0.f, nullptr, nullptr);
    __syncthreads();
    // T2 = relu(xcn @ xcn_w1 + b) -> P0
    layer_sb<0>(PH[1], PL[1], WFH + 3 * 65536, WFL + 3 * 65536, bcn1,
                PH[0], PL[0], nullptr, nullptr, nullptr, 0, 0.f, nullptr, nullptr);
    __syncthreads();
    // z = relu(T2 @ xcn_w2 + b)*beta + XIJ -> P1
    layer_sb<1>(PH[0], PL[0], WFH + 4 * 65536, WFL + 4 * 65536, bcn2,
                PH[1], PL[1], FO, nullptr, nullptr, 0, beta, nullptr, nullptr);
    __syncthreads();
    // out = relu(z @ lin_w1 + b) @ w2  (gemv fused)
    layer_sb<4>(PH[1], PL[1], WFH + 5 * 65536, WFL + 5 * 65536, blin1,
                nullptr, nullptr, nullptr, nullptr, nullptr, 0, 0.f, w2, out32);
    __syncthreads();
    if (t < 32) out[e0 + t] = out32[t] + b2[0];
}

extern "C" void kernel_launch(void* const* d_in, const int* in_sizes, int n_in,
                              void* d_out, int out_size, void* d_ws, size_t ws_size,
                              hipStream_t stream) {
    const float* x       = (const float*)d_in[0];
    const float* adj     = (const float*)d_in[1];
    const int*   tar_ei  = (const int*)  d_in[2];
    const float* xlin_w1 = (const float*)d_in[3];
    const float* xlin_b1 = (const float*)d_in[4];
    const float* xlin_w2 = (const float*)d_in[5];
    const float* xlin_b2 = (const float*)d_in[6];
    const float* xcn_w1  = (const float*)d_in[7];
    const float* xcn_b1  = (const float*)d_in[8];
    const float* xcn_w2  = (const float*)d_in[9];
    const float* xcn_b2  = (const float*)d_in[10];
    const float* xij_w   = (const float*)d_in[11];
    const float* xij_b   = (const float*)d_in[12];
    const float* lin_w1  = (const float*)d_in[13];
    const float* lin_b1  = (const float*)d_in[14];
    const float* lin_w2  = (const float*)d_in[15];
    const float* lin_b2  = (const float*)d_in[16];
    const float* beta    = (const float*)d_in[17];
    float* out = (float*)d_out;

    char* ws = (char*)d_ws;
    const size_t MB = 1024 * 1024;
    unsigned long long* bits = (unsigned long long*)(ws);       // 8 MB
    short* WFH  = (short*)(ws +  8 * MB);   // 768 KB
    short* WFL  = (short*)(ws +  9 * MB);   // 768 KB
    float* Hbuf = (float*)(ws + 10 * MB);   // 8 MB

    WPtrs wp;
    wp.p[0] = xlin_w1; wp.p[1] = xlin_w2; wp.p[2] = xij_w;
    wp.p[3] = xcn_w1;  wp.p[4] = xcn_w2;  wp.p[5] = lin_w1;

    hipLaunchKernelGGL(k_prep, dim3(48 + 1024), dim3(256), 0, stream,
                       adj, bits, wp, WFH, WFL);
    hipLaunchKernelGGL(k_fused_x, dim3(N_NODES / 32), dim3(512), 0, stream,
                       x, WFH, WFL, xlin_b1, xlin_b2, Hbuf);
    hipLaunchKernelGGL(k_fused_edge, dim3(E_EDGES / 32), dim3(512), 0, stream,
                       bits, x, Hbuf, tar_ei, WFH, WFL,
                       xij_b, xcn_b1, xcn_b2, lin_b1, beta, lin_w2, lin_b2, out);
}